// Round 1
// baseline (142.403 us; speedup 1.0000x reference)
//
#include <hip/hip_runtime.h>
#include <cstddef>

namespace {

constexpr int NB    = 8;
constexpr int LQn   = 2048;
constexpr int DM    = 256;
constexpr int S_TOT = 3840;   // 2048+1024+512+256

// ---------------------------------------------------------------------------
// f32 tiled GEMM: out[r][c] = dot(A[r,:256], W[c,:256]) + bias[c]
// A: (R,256) row-major.  W: (C,256) row-major (i.e. out = A @ W^T + b).
// 64x64 tile, K-step 32, 256 threads, 4x4 microtile.
// LDS tiles stored transposed [k][m] (pad to 68 -> rows 272B, 16B-aligned)
// so the inner loop is 2x ds_read_b128 + 16 v_fmac per k.
// If Wb != nullptr, column tiles >= 128 switch to Wb/bb (col-128): lets one
// launch produce [offs | attn_logits] from two weight matrices.
// ---------------------------------------------------------------------------
__global__ __launch_bounds__(256) void gemm_f32_k(
    const float* __restrict__ A,
    const float* __restrict__ Wa, const float* __restrict__ ba,
    const float* __restrict__ Wb, const float* __restrict__ bb,
    float* __restrict__ out)
{
  __shared__ float As[32][68];
  __shared__ float Bs[32][68];
  const int tid = threadIdx.x;
  const int r0  = blockIdx.x * 64;
  const int c0  = blockIdx.y * 64;

  const float* W    = Wa;
  const float* bias = ba;
  int cw0 = c0;
  if (Wb != nullptr && c0 >= 128) { W = Wb; bias = bb; cw0 = c0 - 128; }

  const int tm = (tid & 15) * 4;   // 0..60
  const int tn = (tid >> 4) * 4;   // 0..60
  float acc[4][4] = {{0.f, 0.f, 0.f, 0.f}};

  for (int k0 = 0; k0 < DM; k0 += 32) {
    #pragma unroll
    for (int i = 0; i < 2; ++i) {
      const int f  = tid + i * 256;     // 0..511
      const int r  = f >> 3;            // 0..63 row within tile
      const int k4 = (f & 7) * 4;       // 0..28
      const float4 va = *reinterpret_cast<const float4*>(
          &A[(size_t)(r0 + r) * DM + k0 + k4]);
      const float4 vb = *reinterpret_cast<const float4*>(
          &W[(size_t)(cw0 + r) * DM + k0 + k4]);
      As[k4 + 0][r] = va.x; As[k4 + 1][r] = va.y;
      As[k4 + 2][r] = va.z; As[k4 + 3][r] = va.w;
      Bs[k4 + 0][r] = vb.x; Bs[k4 + 1][r] = vb.y;
      Bs[k4 + 2][r] = vb.z; Bs[k4 + 3][r] = vb.w;
    }
    __syncthreads();
    #pragma unroll
    for (int kk = 0; kk < 32; ++kk) {
      const float4 a4 = *reinterpret_cast<const float4*>(&As[kk][tm]);
      const float4 b4 = *reinterpret_cast<const float4*>(&Bs[kk][tn]);
      const float a[4] = {a4.x, a4.y, a4.z, a4.w};
      const float b[4] = {b4.x, b4.y, b4.z, b4.w};
      #pragma unroll
      for (int i = 0; i < 4; ++i)
        #pragma unroll
        for (int j = 0; j < 4; ++j)
          acc[i][j] = fmaf(a[i], b[j], acc[i][j]);
    }
    __syncthreads();
  }

  const float4 b4 = *reinterpret_cast<const float4*>(&bias[cw0 + tn]);
  #pragma unroll
  for (int i = 0; i < 4; ++i) {
    float4 o;
    o.x = acc[i][0] + b4.x;
    o.y = acc[i][1] + b4.y;
    o.z = acc[i][2] + b4.z;
    o.w = acc[i][3] + b4.w;
    *reinterpret_cast<float4*>(&out[(size_t)(r0 + tm + i) * DM + c0 + tn]) = o;
  }
}

// ---------------------------------------------------------------------------
// Per-query sampler: block = 256 threads = one (n,q).
// proj row: [0:128] = offset logits (m*16+l*4+p), [128:256] = attn logits.
// Thread t -> (m = t>>5, d = t&31) accumulates 16 (l,p) bilinear samples.
// ---------------------------------------------------------------------------
__global__ __launch_bounds__(256) void sample_k(
    const float* __restrict__ proj,   // (N*LQ, 256)
    const float* __restrict__ refp,   // (N, LQ, 4)
    const float* __restrict__ value,  // (N, 3840, 256)  c = m*32+d
    float* __restrict__ out)          // (N, LQ, 256)
{
  __shared__ float loc_s[128];
  __shared__ float logit_s[128];
  __shared__ float attn_s[128];

  const int row = blockIdx.x;        // n*LQ + q
  const int n   = row >> 11;
  const int t   = threadIdx.x;

  const int   lens[4]   = {2048, 1024, 512, 256};
  const int   starts[4] = {0, 2048, 3072, 3584};
  const float flens[4]  = {2048.f, 1024.f, 512.f, 256.f};

  if (t < 128) {
    const float off = proj[(size_t)row * DM + t];
    const int   l   = (t >> 2) & 3;
    const float ref = refp[(size_t)row * 4 + l];
    loc_s[t]   = ref + off / flens[l];
    logit_s[t] = proj[(size_t)row * DM + 128 + t];
  }
  __syncthreads();

  if (t < 8) {  // one thread per head: softmax over 16 (l,p)
    float mx = -1e30f;
    #pragma unroll
    for (int i = 0; i < 16; ++i) mx = fmaxf(mx, logit_s[t * 16 + i]);
    float e[16];
    float s = 0.f;
    #pragma unroll
    for (int i = 0; i < 16; ++i) {
      e[i] = __expf(logit_s[t * 16 + i] - mx);
      s += e[i];
    }
    const float inv = 1.f / s;
    #pragma unroll
    for (int i = 0; i < 16; ++i) attn_s[t * 16 + i] = e[i] * inv;
  }
  __syncthreads();

  const int m = t >> 5;
  const int d = t & 31;
  const float* vbase = value + (size_t)n * S_TOT * DM + m * 32 + d;

  float acc = 0.f;
  #pragma unroll
  for (int l = 0; l < 4; ++l) {
    const int T  = lens[l];
    const int st = starts[l];
    #pragma unroll
    for (int p = 0; p < 4; ++p) {
      const int   idx = m * 16 + l * 4 + p;
      const float a   = attn_s[idx];
      const float x   = loc_s[idx];
      const float ix  = x * (float)T - 0.5f;
      const float fl  = floorf(ix);
      const float w1  = ix - fl;
      const int   i0  = (int)fl;
      const int   i1  = i0 + 1;
      const float v0 = (i0 >= 0 && i0 < T) ? vbase[(size_t)(st + i0) * DM] : 0.f;
      const float v1 = (i1 >= 0 && i1 < T) ? vbase[(size_t)(st + i1) * DM] : 0.f;
      acc += a * ((1.f - w1) * v0 + w1 * v1);
    }
  }
  out[(size_t)row * DM + t] = acc;
}

}  // namespace

extern "C" void kernel_launch(void* const* d_in, const int* in_sizes, int n_in,
                              void* d_out, int out_size, void* d_ws, size_t ws_size,
                              hipStream_t stream) {
  const float* query  = (const float*)d_in[0];   // (8,2048,256)
  const float* refp   = (const float*)d_in[1];   // (8,2048,4,1)
  const float* inflat = (const float*)d_in[2];   // (8,3840,256)
  // d_in[3] lens, d_in[4] level_start: compile-time constants here
  const float* W_val  = (const float*)d_in[5];   // (256,256)
  const float* b_val  = (const float*)d_in[6];   // (256,)
  const float* W_off  = (const float*)d_in[7];   // (128,256)
  const float* b_off  = (const float*)d_in[8];   // (128,)
  const float* W_attn = (const float*)d_in[9];   // (128,256)
  const float* b_attn = (const float*)d_in[10];  // (128,)
  float* out = (float*)d_out;

  // workspace layout: value (30720*256 f32) | proj (16384*256 f32)
  float* value = (float*)d_ws;
  float* proj  = value + (size_t)NB * S_TOT * DM;

  dim3 blk(256);

  // value = input_flatten @ W_val^T + b_val   (30720 x 256)
  gemm_f32_k<<<dim3((NB * S_TOT) / 64, DM / 64), blk, 0, stream>>>(
      inflat, W_val, b_val, nullptr, nullptr, value);

  // proj = query @ [W_off | W_attn]^T + [b_off | b_attn]   (16384 x 256)
  gemm_f32_k<<<dim3((NB * LQn) / 64, DM / 64), blk, 0, stream>>>(
      query, W_off, b_off, W_attn, b_attn, proj);

  // softmax + bilinear sampling + head-mix
  sample_k<<<dim3(NB * LQn), blk, 0, stream>>>(proj, refp, value, out);
}

// Round 2
// 79.525 us; speedup vs baseline: 1.7907x; 1.7907x over previous
//
#include <hip/hip_runtime.h>
#include <cstddef>

namespace {

constexpr int NB    = 8;
constexpr int LQn   = 2048;
constexpr int DM    = 256;
constexpr int S_TOT = 3840;   // 2048+1024+512+256

typedef __attribute__((ext_vector_type(8))) short short8;
typedef __attribute__((ext_vector_type(4))) float f32x4;

__device__ inline unsigned short f2bf(float f) {
  union { float f; unsigned u; } v; v.f = f;
  const unsigned u = v.u;
  return (unsigned short)((u + 0x7FFFu + ((u >> 16) & 1u)) >> 16);  // RNE
}

// ---------------------------------------------------------------------------
// bf16-MFMA GEMM with fused f32->bf16 conversion (reg-staged).
// out[r][c] = dot(A[r,:256], W[c,:256]) + bias[c];  A:(R,256), W:(C,256) row-major.
// Tile 128x128, BK=64, 256 threads = 4 waves (2x2), wave = 64x64 out,
// 4x4 fragments of mfma_f32_16x16x32_bf16.
// LDS tiles [128][64] bf16 with T2 XOR swizzle (byte ^= (row&7)<<4) on both
// the ds_write (staging) and ds_read (fragment) sides.
// If Wb != nullptr, column tiles >= 128 use Wb/bb (the proj kernel producing
// [offs | attn_logits] in one launch; 128-col split = tile boundary).
// ---------------------------------------------------------------------------
__global__ __launch_bounds__(256) void gemm_bf16_k(
    const float* __restrict__ A,
    const float* __restrict__ Wa, const float* __restrict__ ba,
    const float* __restrict__ Wb, const float* __restrict__ bb,
    float* __restrict__ out)
{
  __shared__ short As[128 * 64];
  __shared__ short Bs[128 * 64];

  const int tid  = threadIdx.x;
  const int lane = tid & 63;
  const int wid  = tid >> 6;
  const int wm   = wid >> 1;       // 0..1
  const int wn   = wid & 1;        // 0..1
  const int r0   = blockIdx.x * 128;
  const int c0   = blockIdx.y * 128;

  const float* W    = Wa;
  const float* bias = ba;
  int cw0 = c0;
  if (Wb != nullptr && c0 >= 128) { W = Wb; bias = bb; cw0 = c0 - 128; }

  f32x4 acc[4][4] = {};

  // staging assignment: 1024 chunks of 8 bf16; chunk = row*8 + kg
  const int st_row = (tid * 4) >> 3;        // rows covered: thread t -> chunks t*? ...
  // (each thread handles chunks tid + i*256, i=0..3)

  // bias values for this lane's 4 N-fragments
  float bv[4];
  #pragma unroll
  for (int ni = 0; ni < 4; ++ni)
    bv[ni] = bias[cw0 + wn * 64 + ni * 16 + (lane & 15)];

  for (int k0 = 0; k0 < DM; k0 += 64) {
    // ---- stage A and B tiles (f32 -> bf16, swizzled ds_write_b128) ----
    #pragma unroll
    for (int i = 0; i < 4; ++i) {
      const int ch  = tid + i * 256;   // 0..1023
      const int row = ch >> 3;         // 0..127
      const int kg  = ch & 7;          // 0..7  (8 bf16 per chunk)
      const size_t goff = (size_t)(r0 + row) * DM + k0 + kg * 8;
      const f32x4 a0 = *reinterpret_cast<const f32x4*>(&A[goff]);
      const f32x4 a1 = *reinterpret_cast<const f32x4*>(&A[goff + 4]);
      const size_t woff = (size_t)(cw0 + row) * DM + k0 + kg * 8;
      const f32x4 w0 = *reinterpret_cast<const f32x4*>(&W[woff]);
      const f32x4 w1 = *reinterpret_cast<const f32x4*>(&W[woff + 4]);
      short8 sa, sw;
      #pragma unroll
      for (int j = 0; j < 4; ++j) {
        sa[j]     = (short)f2bf(a0[j]);
        sa[j + 4] = (short)f2bf(a1[j]);
        sw[j]     = (short)f2bf(w0[j]);
        sw[j + 4] = (short)f2bf(w1[j]);
      }
      const int byte = row * 128 + ((kg * 16) ^ ((row & 7) << 4));
      *reinterpret_cast<short8*>(reinterpret_cast<char*>(As) + byte) = sa;
      *reinterpret_cast<short8*>(reinterpret_cast<char*>(Bs) + byte) = sw;
    }
    __syncthreads();

    // ---- 2 k-slices of 32, 16 MFMA each ----
    #pragma unroll
    for (int ks = 0; ks < 2; ++ks) {
      const int kb = (ks * 32 + (lane >> 4) * 8) * 2;  // byte-in-row, 16B aligned
      short8 af[4], bf[4];
      #pragma unroll
      for (int mi = 0; mi < 4; ++mi) {
        const int row = wm * 64 + mi * 16 + (lane & 15);
        const int byte = row * 128 + (kb ^ ((row & 7) << 4));
        af[mi] = *reinterpret_cast<const short8*>(
            reinterpret_cast<const char*>(As) + byte);
      }
      #pragma unroll
      for (int ni = 0; ni < 4; ++ni) {
        const int col = wn * 64 + ni * 16 + (lane & 15);
        const int byte = col * 128 + (kb ^ ((col & 7) << 4));
        bf[ni] = *reinterpret_cast<const short8*>(
            reinterpret_cast<const char*>(Bs) + byte);
      }
      #pragma unroll
      for (int mi = 0; mi < 4; ++mi)
        #pragma unroll
        for (int ni = 0; ni < 4; ++ni)
          acc[mi][ni] = __builtin_amdgcn_mfma_f32_16x16x32_bf16(
              af[mi], bf[ni], acc[mi][ni], 0, 0, 0);
    }
    __syncthreads();
  }

  // ---- epilogue: C/D layout col=lane&15, row=(lane>>4)*4+reg ----
  #pragma unroll
  for (int mi = 0; mi < 4; ++mi) {
    const int row = r0 + wm * 64 + mi * 16 + (lane >> 4) * 4;
    #pragma unroll
    for (int ni = 0; ni < 4; ++ni) {
      const int col = c0 + wn * 64 + ni * 16 + (lane & 15);
      #pragma unroll
      for (int j = 0; j < 4; ++j)
        out[(size_t)(row + j) * DM + col] = acc[mi][ni][j] + bv[ni];
    }
  }
}

// ---------------------------------------------------------------------------
// Per-query sampler: block = 256 threads = one (n,q).
// proj row: [0:128] = offset logits (m*16+l*4+p), [128:256] = attn logits.
// Thread t -> (m = t>>5, d = t&31) accumulates 16 (l,p) bilinear samples.
// ---------------------------------------------------------------------------
__global__ __launch_bounds__(256) void sample_k(
    const float* __restrict__ proj,   // (N*LQ, 256)
    const float* __restrict__ refp,   // (N, LQ, 4)
    const float* __restrict__ value,  // (N, 3840, 256)  c = m*32+d
    float* __restrict__ out)          // (N, LQ, 256)
{
  __shared__ float loc_s[128];
  __shared__ float logit_s[128];
  __shared__ float attn_s[128];

  const int row = blockIdx.x;        // n*LQ + q
  const int n   = row >> 11;
  const int t   = threadIdx.x;

  const int   lens[4]   = {2048, 1024, 512, 256};
  const int   starts[4] = {0, 2048, 3072, 3584};
  const float flens[4]  = {2048.f, 1024.f, 512.f, 256.f};

  if (t < 128) {
    const float off = proj[(size_t)row * DM + t];
    const int   l   = (t >> 2) & 3;
    const float ref = refp[(size_t)row * 4 + l];
    loc_s[t]   = ref + off / flens[l];
    logit_s[t] = proj[(size_t)row * DM + 128 + t];
  }
  __syncthreads();

  if (t < 8) {  // one thread per head: softmax over 16 (l,p)
    float mx = -1e30f;
    #pragma unroll
    for (int i = 0; i < 16; ++i) mx = fmaxf(mx, logit_s[t * 16 + i]);
    float e[16];
    float s = 0.f;
    #pragma unroll
    for (int i = 0; i < 16; ++i) {
      e[i] = __expf(logit_s[t * 16 + i] - mx);
      s += e[i];
    }
    const float inv = 1.f / s;
    #pragma unroll
    for (int i = 0; i < 16; ++i) attn_s[t * 16 + i] = e[i] * inv;
  }
  __syncthreads();

  const int m = t >> 5;
  const int d = t & 31;
  const float* vbase = value + (size_t)n * S_TOT * DM + m * 32 + d;

  float acc = 0.f;
  #pragma unroll
  for (int l = 0; l < 4; ++l) {
    const int T  = lens[l];
    const int st = starts[l];
    #pragma unroll
    for (int p = 0; p < 4; ++p) {
      const int   idx = m * 16 + l * 4 + p;
      const float a   = attn_s[idx];
      const float x   = loc_s[idx];
      const float ix  = x * (float)T - 0.5f;
      const float fl  = floorf(ix);
      const float w1  = ix - fl;
      const int   i0  = (int)fl;
      const int   i1  = i0 + 1;
      const float v0 = (i0 >= 0 && i0 < T) ? vbase[(size_t)(st + i0) * DM] : 0.f;
      const float v1 = (i1 >= 0 && i1 < T) ? vbase[(size_t)(st + i1) * DM] : 0.f;
      acc += a * ((1.f - w1) * v0 + w1 * v1);
    }
  }
  out[(size_t)row * DM + t] = acc;
}

}  // namespace

extern "C" void kernel_launch(void* const* d_in, const int* in_sizes, int n_in,
                              void* d_out, int out_size, void* d_ws, size_t ws_size,
                              hipStream_t stream) {
  const float* query  = (const float*)d_in[0];   // (8,2048,256)
  const float* refp   = (const float*)d_in[1];   // (8,2048,4,1)
  const float* inflat = (const float*)d_in[2];   // (8,3840,256)
  const float* W_val  = (const float*)d_in[5];   // (256,256)
  const float* b_val  = (const float*)d_in[6];   // (256,)
  const float* W_off  = (const float*)d_in[7];   // (128,256)
  const float* b_off  = (const float*)d_in[8];   // (128,)
  const float* W_attn = (const float*)d_in[9];   // (128,256)
  const float* b_attn = (const float*)d_in[10];  // (128,)
  float* out = (float*)d_out;

  // workspace layout: value (30720*256 f32) | proj (16384*256 f32)
  float* value = (float*)d_ws;
  float* proj  = value + (size_t)NB * S_TOT * DM;

  dim3 blk(256);

  // value = input_flatten @ W_val^T + b_val   (30720 x 256)
  gemm_bf16_k<<<dim3((NB * S_TOT) / 128, DM / 128), blk, 0, stream>>>(
      inflat, W_val, b_val, nullptr, nullptr, value);

  // proj = query @ [W_off | W_attn]^T + [b_off | b_attn]   (16384 x 256)
  gemm_bf16_k<<<dim3((NB * LQn) / 128, DM / 128), blk, 0, stream>>>(
      query, W_off, b_off, W_attn, b_attn, proj);

  // softmax + bilinear sampling + head-mix
  sample_k<<<dim3(NB * LQn), blk, 0, stream>>>(proj, refp, value, out);
}

// Round 3
// 55.140 us; speedup vs baseline: 2.5826x; 1.4422x over previous
//
#include <hip/hip_runtime.h>
#include <cstddef>

namespace {

constexpr int NB    = 8;
constexpr int LQn   = 2048;
constexpr int DM    = 256;
constexpr int S_TOT = 3840;   // 2048+1024+512+256

typedef __attribute__((ext_vector_type(8))) short short8;
typedef __attribute__((ext_vector_type(4))) float f32x4;

__device__ inline unsigned short f2bf(float f) {
  union { float f; unsigned u; } v; v.f = f;
  const unsigned u = v.u;
  return (unsigned short)((u + 0x7FFFu + ((u >> 16) & 1u)) >> 16);  // RNE
}
__device__ inline float bf2f(short s) {
  union { unsigned u; float f; } v;
  v.u = ((unsigned)(unsigned short)s) << 16;
  return v.f;
}

// ---------------------------------------------------------------------------
// bf16-MFMA GEMM with fused f32->bf16 conversion (reg-staged).
// out[r][c] = dot(A[r,:256], W[c,:256]) + bias[c];  A:(R,256), W:(C,256) row-major.
// Tile 128x128, BK=64, 256 threads = 4 waves (2x2), wave = 64x64 out,
// 4x4 fragments of mfma_f32_16x16x32_bf16.
// LDS tiles [128][64] bf16, T2 XOR swizzle (byte ^= (row&7)<<4) on both sides.
// OutT = float or bf16 (value GEMM stores bf16 for the sampler's gathers).
// If Wb != nullptr, column tiles >= 128 use Wb/bb ([offs | attn] proj GEMM).
// ---------------------------------------------------------------------------
template <typename OutT>
__global__ __launch_bounds__(256) void gemm_bf16_k(
    const float* __restrict__ A,
    const float* __restrict__ Wa, const float* __restrict__ ba,
    const float* __restrict__ Wb, const float* __restrict__ bb,
    OutT* __restrict__ out)
{
  __shared__ short As[128 * 64];
  __shared__ short Bs[128 * 64];

  const int tid  = threadIdx.x;
  const int lane = tid & 63;
  const int wid  = tid >> 6;
  const int wm   = wid >> 1;       // 0..1
  const int wn   = wid & 1;        // 0..1
  const int r0   = blockIdx.x * 128;
  const int c0   = blockIdx.y * 128;

  const float* W    = Wa;
  const float* bias = ba;
  int cw0 = c0;
  if (Wb != nullptr && c0 >= 128) { W = Wb; bias = bb; cw0 = c0 - 128; }

  f32x4 acc[4][4] = {};

  float bv[4];
  #pragma unroll
  for (int ni = 0; ni < 4; ++ni)
    bv[ni] = bias[cw0 + wn * 64 + ni * 16 + (lane & 15)];

  for (int k0 = 0; k0 < DM; k0 += 64) {
    #pragma unroll
    for (int i = 0; i < 4; ++i) {
      const int ch  = tid + i * 256;   // 0..1023
      const int row = ch >> 3;         // 0..127
      const int kg  = ch & 7;          // 0..7  (8 bf16 per chunk)
      const size_t goff = (size_t)(r0 + row) * DM + k0 + kg * 8;
      const f32x4 a0 = *reinterpret_cast<const f32x4*>(&A[goff]);
      const f32x4 a1 = *reinterpret_cast<const f32x4*>(&A[goff + 4]);
      const size_t woff = (size_t)(cw0 + row) * DM + k0 + kg * 8;
      const f32x4 w0 = *reinterpret_cast<const f32x4*>(&W[woff]);
      const f32x4 w1 = *reinterpret_cast<const f32x4*>(&W[woff + 4]);
      short8 sa, sw;
      #pragma unroll
      for (int j = 0; j < 4; ++j) {
        sa[j]     = (short)f2bf(a0[j]);
        sa[j + 4] = (short)f2bf(a1[j]);
        sw[j]     = (short)f2bf(w0[j]);
        sw[j + 4] = (short)f2bf(w1[j]);
      }
      const int byte = row * 128 + ((kg * 16) ^ ((row & 7) << 4));
      *reinterpret_cast<short8*>(reinterpret_cast<char*>(As) + byte) = sa;
      *reinterpret_cast<short8*>(reinterpret_cast<char*>(Bs) + byte) = sw;
    }
    __syncthreads();

    #pragma unroll
    for (int ks = 0; ks < 2; ++ks) {
      const int kb = (ks * 32 + (lane >> 4) * 8) * 2;  // byte-in-row, 16B aligned
      short8 af[4], bf[4];
      #pragma unroll
      for (int mi = 0; mi < 4; ++mi) {
        const int row = wm * 64 + mi * 16 + (lane & 15);
        const int byte = row * 128 + (kb ^ ((row & 7) << 4));
        af[mi] = *reinterpret_cast<const short8*>(
            reinterpret_cast<const char*>(As) + byte);
      }
      #pragma unroll
      for (int ni = 0; ni < 4; ++ni) {
        const int col = wn * 64 + ni * 16 + (lane & 15);
        const int byte = col * 128 + (kb ^ ((col & 7) << 4));
        bf[ni] = *reinterpret_cast<const short8*>(
            reinterpret_cast<const char*>(Bs) + byte);
      }
      #pragma unroll
      for (int mi = 0; mi < 4; ++mi)
        #pragma unroll
        for (int ni = 0; ni < 4; ++ni)
          acc[mi][ni] = __builtin_amdgcn_mfma_f32_16x16x32_bf16(
              af[mi], bf[ni], acc[mi][ni], 0, 0, 0);
    }
    __syncthreads();
  }

  // epilogue: C/D layout col=lane&15, row=(lane>>4)*4+reg
  #pragma unroll
  for (int mi = 0; mi < 4; ++mi) {
    const int row = r0 + wm * 64 + mi * 16 + (lane >> 4) * 4;
    #pragma unroll
    for (int ni = 0; ni < 4; ++ni) {
      const int col = c0 + wn * 64 + ni * 16 + (lane & 15);
      #pragma unroll
      for (int j = 0; j < 4; ++j) {
        const float v = acc[mi][ni][j] + bv[ni];
        if constexpr (__is_same(OutT, float)) {
          out[(size_t)(row + j) * DM + col] = v;
        } else {
          reinterpret_cast<unsigned short*>(out)[(size_t)(row + j) * DM + col] =
              f2bf(v);
        }
      }
    }
  }
}

// ---------------------------------------------------------------------------
// Sampler: block = 256 threads = 8 queries. Thread -> (q = t>>5, m = (t>>2)&7,
// dgroup = t&3 -> 8 channels). bf16 value, short8 (16B) gathers,
// clamp + zero-weight for out-of-range taps.
// loc/attn in LDS with 17-stride per-head padding (breaks the m-stride-16
// 2-bank pattern on the sampling-phase ds_reads).
// ---------------------------------------------------------------------------
#define SIDX(m, lp) ((m) * 17 + (lp))

__global__ __launch_bounds__(256) void sample_k(
    const float* __restrict__ proj,             // (N*LQ, 256)
    const float* __restrict__ refp,             // (N, LQ, 4)
    const unsigned short* __restrict__ value,   // (N, 3840, 256) bf16, c=m*32+d
    float* __restrict__ out)                    // (N, LQ, 256)
{
  constexpr int QPB = 8;
  __shared__ float proj_s[QPB][256];
  __shared__ float loc_s[QPB][136];
  __shared__ float attn_s[QPB][136];
  __shared__ float ref_s[QPB][4];

  const int row0 = blockIdx.x * QPB;
  const int n    = row0 >> 11;          // LQ=2048, QPB divides it
  const int t    = threadIdx.x;

  // stage proj rows (8 x 256 f32) and ref points
  {
    const f32x4* src = reinterpret_cast<const f32x4*>(proj + (size_t)row0 * DM);
    f32x4* dst = reinterpret_cast<f32x4*>(&proj_s[0][0]);
    dst[t]       = src[t];
    dst[t + 256] = src[t + 256];
  }
  if (t < QPB * 4) reinterpret_cast<float*>(ref_s)[t] = refp[(size_t)row0 * 4 + t];
  __syncthreads();

  // loc: 8 x 128 entries; thread -> q = t>>5, 4 consecutive j
  {
    const float inv_flens[4] = {1.f / 2048.f, 1.f / 1024.f, 1.f / 512.f, 1.f / 256.f};
    const int q  = t >> 5;
    const int j0 = (t & 31) * 4;
    #pragma unroll
    for (int jj = 0; jj < 4; ++jj) {
      const int j = j0 + jj;
      const int l = (j >> 2) & 3;
      loc_s[q][SIDX(j >> 4, j & 15)] = ref_s[q][l] + proj_s[q][j] * inv_flens[l];
    }
  }
  // softmax per (q, head): 64 units
  if (t < 64) {
    const int q = t >> 3, m = t & 7;
    const float* lg = &proj_s[q][128 + m * 16];
    float mx = -1e30f;
    #pragma unroll
    for (int i = 0; i < 16; ++i) mx = fmaxf(mx, lg[i]);
    float e[16], s = 0.f;
    #pragma unroll
    for (int i = 0; i < 16; ++i) { e[i] = __expf(lg[i] - mx); s += e[i]; }
    const float inv = 1.f / s;
    #pragma unroll
    for (int i = 0; i < 16; ++i) attn_s[q][SIDX(m, i)] = e[i] * inv;
  }
  __syncthreads();

  const int lens[4]   = {2048, 1024, 512, 256};
  const int starts[4] = {0, 2048, 3072, 3584};

  const int q  = t >> 5;
  const int m  = (t >> 2) & 7;
  const int dg = t & 3;
  const int row = row0 + q;
  const unsigned short* vbase =
      value + (size_t)n * S_TOT * DM + m * 32 + dg * 8;

  float acc[8] = {};
  #pragma unroll
  for (int l = 0; l < 4; ++l) {
    const int   T  = lens[l];
    const int   st = starts[l];
    #pragma unroll
    for (int p = 0; p < 4; ++p) {
      const int   lp = l * 4 + p;
      const float a  = attn_s[q][SIDX(m, lp)];
      const float x  = loc_s[q][SIDX(m, lp)];
      const float ix = x * (float)T - 0.5f;
      const float fl = floorf(ix);
      const float w1 = ix - fl;
      const int   i0 = (int)fl;
      const int   i1 = i0 + 1;
      const float wa = (i0 >= 0 && i0 < T) ? a * (1.f - w1) : 0.f;
      const float wb = (i1 >= 0 && i1 < T) ? a * w1 : 0.f;
      const int   c0i = st + min(max(i0, 0), T - 1);
      const int   c1i = st + min(max(i1, 0), T - 1);
      const short8 v0 = *reinterpret_cast<const short8*>(&vbase[(size_t)c0i * DM]);
      const short8 v1 = *reinterpret_cast<const short8*>(&vbase[(size_t)c1i * DM]);
      #pragma unroll
      for (int j = 0; j < 8; ++j)
        acc[j] = fmaf(wa, bf2f(v0[j]), fmaf(wb, bf2f(v1[j]), acc[j]));
    }
  }

  float* op = &out[(size_t)row * DM + m * 32 + dg * 8];
  f32x4 o0 = {acc[0], acc[1], acc[2], acc[3]};
  f32x4 o1 = {acc[4], acc[5], acc[6], acc[7]};
  *reinterpret_cast<f32x4*>(op)     = o0;
  *reinterpret_cast<f32x4*>(op + 4) = o1;
}

}  // namespace

extern "C" void kernel_launch(void* const* d_in, const int* in_sizes, int n_in,
                              void* d_out, int out_size, void* d_ws, size_t ws_size,
                              hipStream_t stream) {
  const float* query  = (const float*)d_in[0];   // (8,2048,256)
  const float* refp   = (const float*)d_in[1];   // (8,2048,4,1)
  const float* inflat = (const float*)d_in[2];   // (8,3840,256)
  const float* W_val  = (const float*)d_in[5];   // (256,256)
  const float* b_val  = (const float*)d_in[6];   // (256,)
  const float* W_off  = (const float*)d_in[7];   // (128,256)
  const float* b_off  = (const float*)d_in[8];   // (128,)
  const float* W_attn = (const float*)d_in[9];   // (128,256)
  const float* b_attn = (const float*)d_in[10];  // (128,)
  float* out = (float*)d_out;

  // workspace: value bf16 (30720*256 = 15.73 MB) | proj f32 (16384*256 f32)
  unsigned short* value_bf = (unsigned short*)d_ws;
  float* proj = (float*)((char*)d_ws + (size_t)NB * S_TOT * DM * sizeof(unsigned short));

  dim3 blk(256);

  // value(bf16) = input_flatten @ W_val^T + b_val   (30720 x 256)
  gemm_bf16_k<unsigned short><<<dim3((NB * S_TOT) / 128, DM / 128), blk, 0, stream>>>(
      inflat, W_val, b_val, nullptr, nullptr, value_bf);

  // proj(f32) = query @ [W_off | W_attn]^T + [b_off | b_attn]   (16384 x 256)
  gemm_bf16_k<float><<<dim3((NB * LQn) / 128, DM / 128), blk, 0, stream>>>(
      query, W_off, b_off, W_attn, b_attn, proj);

  // softmax + bilinear sampling + head-mix
  sample_k<<<dim3(NB * LQn / 8), blk, 0, stream>>>(proj, refp, value_bf, out);
}

// Round 4
// 46.669 us; speedup vs baseline: 3.0513x; 1.1815x over previous
//
#include <hip/hip_runtime.h>
#include <cstddef>

namespace {

constexpr int NB    = 8;
constexpr int LQn   = 2048;
constexpr int DM    = 256;
constexpr int S_TOT = 3840;   // 2048+1024+512+256

typedef __attribute__((ext_vector_type(8))) short  short8;
typedef __attribute__((ext_vector_type(4))) float  f32x4;
typedef __attribute__((ext_vector_type(8))) _Float16 half8;
typedef __attribute__((ext_vector_type(2))) _Float16 half2v;

__device__ inline unsigned short f2bf(float f) {
  union { float f; unsigned u; } v; v.f = f;
  const unsigned u = v.u;
  return (unsigned short)((u + 0x7FFFu + ((u >> 16) & 1u)) >> 16);  // RNE
}

// ---------------------------------------------------------------------------
// bf16-MFMA GEMM, fused f32->bf16 staging, f16 output.
// out[r][c] = dot(A[r,:256], W[c,:256]) + bias[c];  A:(R,256), W:(C,256).
// Tile 128x128, BK=64, 4 waves (2x2), 4x4 frags of mfma_f32_16x16x32_bf16.
// LDS [128][64] bf16, T2 XOR swizzle (byte ^= (row&7)<<4) both sides.
// Software pipeline: next k-tile's global loads are issued before the MFMA
// phase; raw s_barrier + manual lgkmcnt(0) (NOT __syncthreads) so the loads'
// vmcnt stays outstanding across the barrier (no vmcnt(0) drain stall).
// If Wb != nullptr, column tiles >= 128 use Wb/bb ([offs|attn] proj GEMM).
// ---------------------------------------------------------------------------
__global__ __launch_bounds__(256) void gemm_bf16_k(
    const float* __restrict__ A,
    const float* __restrict__ Wa, const float* __restrict__ ba,
    const float* __restrict__ Wb, const float* __restrict__ bb,
    _Float16* __restrict__ out)
{
  __shared__ short As[128 * 64];
  __shared__ short Bs[128 * 64];

  const int tid  = threadIdx.x;
  const int lane = tid & 63;
  const int wid  = tid >> 6;
  const int wm   = wid >> 1;
  const int wn   = wid & 1;
  const int r0   = blockIdx.x * 128;
  const int c0   = blockIdx.y * 128;

  const float* W    = Wa;
  const float* bias = ba;
  int cw0 = c0;
  if (Wb != nullptr && c0 >= 128) { W = Wb; bias = bb; cw0 = c0 - 128; }

  f32x4 acc[4][4] = {};

  float bv[4];
  #pragma unroll
  for (int ni = 0; ni < 4; ++ni)
    bv[ni] = bias[cw0 + wn * 64 + ni * 16 + (lane & 15)];

  // prefetch registers: 4 chunks x (A:2 f32x4, W:2 f32x4)
  f32x4 pa0[4], pa1[4], pw0[4], pw1[4];

  auto load_tiles = [&](int k0) {
    #pragma unroll
    for (int i = 0; i < 4; ++i) {
      const int ch  = tid + i * 256;   // 0..1023
      const int row = ch >> 3;         // 0..127
      const int kg  = ch & 7;          // 0..7
      const size_t goff = (size_t)(r0 + row) * DM + k0 + kg * 8;
      pa0[i] = *reinterpret_cast<const f32x4*>(&A[goff]);
      pa1[i] = *reinterpret_cast<const f32x4*>(&A[goff + 4]);
      const size_t woff = (size_t)(cw0 + row) * DM + k0 + kg * 8;
      pw0[i] = *reinterpret_cast<const f32x4*>(&W[woff]);
      pw1[i] = *reinterpret_cast<const f32x4*>(&W[woff + 4]);
    }
  };

  load_tiles(0);

  for (int k = 0; k < 4; ++k) {
    // phase 1: convert + LDS write (waits vmcnt via data dep)
    #pragma unroll
    for (int i = 0; i < 4; ++i) {
      const int ch  = tid + i * 256;
      const int row = ch >> 3;
      const int kg  = ch & 7;
      short8 sa, sw;
      #pragma unroll
      for (int j = 0; j < 4; ++j) {
        sa[j]     = (short)f2bf(pa0[i][j]);
        sa[j + 4] = (short)f2bf(pa1[i][j]);
        sw[j]     = (short)f2bf(pw0[i][j]);
        sw[j + 4] = (short)f2bf(pw1[i][j]);
      }
      const int byte = row * 128 + ((kg * 16) ^ ((row & 7) << 4));
      *reinterpret_cast<short8*>(reinterpret_cast<char*>(As) + byte) = sa;
      *reinterpret_cast<short8*>(reinterpret_cast<char*>(Bs) + byte) = sw;
    }
    // issue next tile's loads; they stay in flight across the barrier + MFMA
    if (k < 3) load_tiles((k + 1) * 64);

    asm volatile("s_waitcnt lgkmcnt(0)" ::: "memory");
    __builtin_amdgcn_sched_barrier(0);
    __builtin_amdgcn_s_barrier();
    __builtin_amdgcn_sched_barrier(0);

    // phase 2: fragments + MFMA
    #pragma unroll
    for (int ks = 0; ks < 2; ++ks) {
      const int kb = (ks * 32 + (lane >> 4) * 8) * 2;
      short8 af[4], bf[4];
      #pragma unroll
      for (int mi = 0; mi < 4; ++mi) {
        const int row = wm * 64 + mi * 16 + (lane & 15);
        const int byte = row * 128 + (kb ^ ((row & 7) << 4));
        af[mi] = *reinterpret_cast<const short8*>(
            reinterpret_cast<const char*>(As) + byte);
      }
      #pragma unroll
      for (int ni = 0; ni < 4; ++ni) {
        const int col = wn * 64 + ni * 16 + (lane & 15);
        const int byte = col * 128 + (kb ^ ((col & 7) << 4));
        bf[ni] = *reinterpret_cast<const short8*>(
            reinterpret_cast<const char*>(Bs) + byte);
      }
      #pragma unroll
      for (int mi = 0; mi < 4; ++mi)
        #pragma unroll
        for (int ni = 0; ni < 4; ++ni)
          acc[mi][ni] = __builtin_amdgcn_mfma_f32_16x16x32_bf16(
              af[mi], bf[ni], acc[mi][ni], 0, 0, 0);
    }

    asm volatile("s_waitcnt lgkmcnt(0)" ::: "memory");
    __builtin_amdgcn_sched_barrier(0);
    __builtin_amdgcn_s_barrier();
    __builtin_amdgcn_sched_barrier(0);
  }

  // epilogue: C/D layout col=lane&15, row=(lane>>4)*4+reg
  #pragma unroll
  for (int mi = 0; mi < 4; ++mi) {
    const int row = r0 + wm * 64 + mi * 16 + (lane >> 4) * 4;
    #pragma unroll
    for (int ni = 0; ni < 4; ++ni) {
      const int col = c0 + wn * 64 + ni * 16 + (lane & 15);
      #pragma unroll
      for (int j = 0; j < 4; ++j)
        out[(size_t)(row + j) * DM + col] = (_Float16)(acc[mi][ni][j] + bv[ni]);
    }
  }
}

// ---------------------------------------------------------------------------
// Sampler v3. Block = 256 threads = 8 queries, XCD-swizzled grid:
// d = blockIdx.x; n = d&7 (one batch per XCD -> its 1.97 MB f16 value slice
// is L2-resident), chunk = d>>3.
// Phase 1 (prep): thread -> (q=t>>5, m=(t>>2)&7, sub=t&3); the 4-lane group
// (q,m) does softmax over its 16 taps via __shfl_xor, then each lane computes
// its 4 taps' bilinear weights (level l == sub) and writes
// {half2(wa,wb), row0*512, row1*512} as uint4 into padded LDS (stride 17 ->
// head stride 272B, conflict-free b128 reads).
// Phase 2 (gather): thread -> (q, m, dg=t&3; 8 channels); per tap:
// ds_read_b128 (4-lane broadcast) + 2x16B f16 loads + 16 fma_mix.
// ---------------------------------------------------------------------------
__global__ __launch_bounds__(256) void sample_k(
    const _Float16* __restrict__ proj,    // (N*LQ, 256) f16
    const float* __restrict__ refp,       // (N, LQ, 4)
    const _Float16* __restrict__ value,   // (N, 3840, 256) f16, c = m*32+d
    float* __restrict__ out)              // (N, LQ, 256)
{
  constexpr int QPB = 8;
  __shared__ _Float16 proj_s[QPB][256];   // 4 KB
  __shared__ float    ref_s[QPB][4];
  __shared__ uint4    tap_s[QPB][8 * 17]; // 17.4 KB, [q][m*17+tap]

  const int d     = blockIdx.x;
  const int n     = d & 7;
  const int chunk = d >> 3;
  const int row0q = n * LQn + chunk * QPB;   // global query row base
  const int t     = threadIdx.x;

  // stage proj rows (8 x 256 f16) and ref points
  reinterpret_cast<half8*>(&proj_s[0][0])[t] =
      reinterpret_cast<const half8*>(proj + (size_t)row0q * DM)[t];
  if (t < QPB * 4)
    reinterpret_cast<float*>(ref_s)[t] = refp[(size_t)row0q * 4 + t];
  __syncthreads();

  const int   lens[4]   = {2048, 1024, 512, 256};
  const int   starts[4] = {0, 2048, 3072, 3584};

  // ---- phase 1: softmax + tap prep ----
  {
    const int q   = t >> 5;
    const int m   = (t >> 2) & 7;
    const int sub = t & 3;              // == level l for this lane's taps
    const int j0  = m * 16 + sub * 4;

    float lg[4], off[4];
    #pragma unroll
    for (int i = 0; i < 4; ++i) {
      lg[i]  = (float)proj_s[q][128 + j0 + i];
      off[i] = (float)proj_s[q][j0 + i];
    }
    float mx = fmaxf(fmaxf(lg[0], lg[1]), fmaxf(lg[2], lg[3]));
    mx = fmaxf(mx, __shfl_xor(mx, 1));
    mx = fmaxf(mx, __shfl_xor(mx, 2));
    float e[4], s = 0.f;
    #pragma unroll
    for (int i = 0; i < 4; ++i) { e[i] = __expf(lg[i] - mx); s += e[i]; }
    s += __shfl_xor(s, 1);
    s += __shfl_xor(s, 2);
    const float inv = 1.f / s;

    const int   T  = lens[sub];
    const int   st = starts[sub];
    const float fT = (float)T;
    const float rf = ref_s[q][sub];
    #pragma unroll
    for (int i = 0; i < 4; ++i) {
      const float a  = e[i] * inv;
      const float ix = fmaf(rf, fT, off[i] - 0.5f);
      const float fl = floorf(ix);
      const float w1 = ix - fl;
      const int   i0 = (int)fl;
      const int   i1 = i0 + 1;
      const float wa = (i0 >= 0 && i0 < T) ? a * (1.f - w1) : 0.f;
      const float wb = (i1 >= 0 && i1 < T) ? a * w1 : 0.f;
      const int   r0b = (st + min(max(i0, 0), T - 1)) * 512;
      const int   r1b = (st + min(max(i1, 0), T - 1)) * 512;
      union { half2v h; unsigned u; } pw;
      pw.h.x = (_Float16)wa; pw.h.y = (_Float16)wb;
      uint4 ent; ent.x = pw.u; ent.y = (unsigned)r0b; ent.z = (unsigned)r1b; ent.w = 0u;
      tap_s[q][m * 17 + sub * 4 + i] = ent;
    }
  }
  __syncthreads();

  // ---- phase 2: gather ----
  const int q  = t >> 5;
  const int m  = (t >> 2) & 7;
  const int dg = t & 3;
  const char* vb = reinterpret_cast<const char*>(value) +
                   (size_t)n * S_TOT * 512 + m * 64 + dg * 16;

  float acc[8] = {};
  #pragma unroll
  for (int tap = 0; tap < 16; ++tap) {
    const uint4 e = tap_s[q][m * 17 + tap];
    union { unsigned u; half2v h; } pw; pw.u = e.x;
    const float wa = (float)pw.h.x;
    const float wb = (float)pw.h.y;
    const half8 v0 = *reinterpret_cast<const half8*>(vb + e.y);
    const half8 v1 = *reinterpret_cast<const half8*>(vb + e.z);
    #pragma unroll
    for (int j = 0; j < 8; ++j)
      acc[j] = fmaf(wa, (float)v0[j], fmaf(wb, (float)v1[j], acc[j]));
  }

  float* op = &out[(size_t)(row0q + q) * DM + m * 32 + dg * 8];
  f32x4 o0 = {acc[0], acc[1], acc[2], acc[3]};
  f32x4 o1 = {acc[4], acc[5], acc[6], acc[7]};
  *reinterpret_cast<f32x4*>(op)     = o0;
  *reinterpret_cast<f32x4*>(op + 4) = o1;
}

}  // namespace

extern "C" void kernel_launch(void* const* d_in, const int* in_sizes, int n_in,
                              void* d_out, int out_size, void* d_ws, size_t ws_size,
                              hipStream_t stream) {
  const float* query  = (const float*)d_in[0];   // (8,2048,256)
  const float* refp   = (const float*)d_in[1];   // (8,2048,4,1)
  const float* inflat = (const float*)d_in[2];   // (8,3840,256)
  const float* W_val  = (const float*)d_in[5];   // (256,256)
  const float* b_val  = (const float*)d_in[6];   // (256,)
  const float* W_off  = (const float*)d_in[7];   // (128,256)
  const float* b_off  = (const float*)d_in[8];   // (128,)
  const float* W_attn = (const float*)d_in[9];   // (128,256)
  const float* b_attn = (const float*)d_in[10];  // (128,)
  float* out = (float*)d_out;

  // workspace: value f16 (30720*256 = 15.73 MB) | proj f16 (16384*256 = 8.4 MB)
  _Float16* value_h = (_Float16*)d_ws;
  _Float16* proj_h  = (_Float16*)((char*)d_ws +
                      (size_t)NB * S_TOT * DM * sizeof(_Float16));

  dim3 blk(256);

  // value(f16) = input_flatten @ W_val^T + b_val   (30720 x 256)
  gemm_bf16_k<<<dim3((NB * S_TOT) / 128, DM / 128), blk, 0, stream>>>(
      inflat, W_val, b_val, nullptr, nullptr, value_h);

  // proj(f16) = query @ [W_off | W_attn]^T + [b_off | b_attn]   (16384 x 256)
  gemm_bf16_k<<<dim3((NB * LQn) / 128, DM / 128), blk, 0, stream>>>(
      query, W_off, b_off, W_attn, b_attn, proj_h);

  // softmax + bilinear sampling + head-mix (XCD-swizzled grid)
  sample_k<<<dim3(NB * LQn / 8), blk, 0, stream>>>(proj_h, refp, value_h, out);
}

// Round 5
// 43.933 us; speedup vs baseline: 3.2414x; 1.0623x over previous
//
#include <hip/hip_runtime.h>
#include <cstddef>

namespace {

constexpr int NB    = 8;
constexpr int LQn   = 2048;
constexpr int DM    = 256;
constexpr int S_TOT = 3840;   // 2048+1024+512+256

typedef __attribute__((ext_vector_type(8))) short  short8;
typedef __attribute__((ext_vector_type(4))) float  f32x4;
typedef __attribute__((ext_vector_type(8))) _Float16 half8;
typedef __attribute__((ext_vector_type(4))) _Float16 half4;
typedef __attribute__((ext_vector_type(2))) _Float16 half2v;

__device__ inline unsigned short f2bf(float f) {
  union { float f; unsigned u; } v; v.f = f;
  const unsigned u = v.u;
  return (unsigned short)((u + 0x7FFFu + ((u >> 16) & 1u)) >> 16);  // RNE
}

// ---------------------------------------------------------------------------
// Merged bf16-MFMA GEMM (value + proj in one launch), fused f32->bf16
// staging, f16 output.  1D grid of 736 blocks:
//   id <  480: value GEMM  (240 row-blocks x 2 col-halves of W_val)
//   id >= 480: proj GEMM   (128 row-blocks x {W_off | W_attn})
// Col-tile partners are ADJACENT ids (id = c + 2*rowblk) so both read the
// same A panel concurrently -> second read is L3-served (fixes the A
// double-fetch of the 2D-grid version).
// Tile 128x128, BK=64, 4 waves (2x2), 4x4 frags of mfma_f32_16x16x32_bf16.
// LDS [128][64] bf16, T2 XOR swizzle (byte ^= (row&7)<<4) both sides.
// Pipeline: next k-tile's global loads issued before the MFMA phase; raw
// s_barrier + lgkmcnt(0) only (vmcnt stays outstanding across the barrier).
// ---------------------------------------------------------------------------
__global__ __launch_bounds__(256) void gemm_bf16_k(
    const float* __restrict__ A_val, const float* __restrict__ A_prj,
    const float* __restrict__ W_val, const float* __restrict__ b_val,
    const float* __restrict__ W_off, const float* __restrict__ b_off,
    const float* __restrict__ W_att, const float* __restrict__ b_att,
    _Float16* __restrict__ out_val, _Float16* __restrict__ out_prj)
{
  __shared__ short As[128 * 64];
  __shared__ short Bs[128 * 64];

  const int tid  = threadIdx.x;
  const int lane = tid & 63;
  const int wid  = tid >> 6;
  const int wm   = wid >> 1;
  const int wn   = wid & 1;

  const int id = blockIdx.x;
  const float *A, *W, *bias;
  _Float16* out;
  int r0, c0;
  if (id < 480) {
    const int rb = id >> 1, c = id & 1;
    A = A_val; out = out_val; r0 = rb * 128; c0 = c * 128;
    W = W_val + (size_t)c0 * DM; bias = b_val + c0;
  } else {
    const int j = id - 480, rb = j >> 1, c = j & 1;
    A = A_prj; out = out_prj; r0 = rb * 128; c0 = c * 128;
    W = c ? W_att : W_off; bias = c ? b_att : b_off;
  }

  f32x4 acc[4][4] = {};

  float bv[4];
  #pragma unroll
  for (int ni = 0; ni < 4; ++ni)
    bv[ni] = bias[wn * 64 + ni * 16 + (lane & 15)];

  f32x4 pa0[4], pa1[4], pw0[4], pw1[4];

  auto load_tiles = [&](int k0) {
    #pragma unroll
    for (int i = 0; i < 4; ++i) {
      const int ch  = tid + i * 256;   // 0..1023
      const int row = ch >> 3;         // 0..127
      const int kg  = ch & 7;          // 0..7
      const size_t goff = (size_t)(r0 + row) * DM + k0 + kg * 8;
      pa0[i] = *reinterpret_cast<const f32x4*>(&A[goff]);
      pa1[i] = *reinterpret_cast<const f32x4*>(&A[goff + 4]);
      const size_t woff = (size_t)row * DM + k0 + kg * 8;
      pw0[i] = *reinterpret_cast<const f32x4*>(&W[woff]);
      pw1[i] = *reinterpret_cast<const f32x4*>(&W[woff + 4]);
    }
  };

  load_tiles(0);

  for (int k = 0; k < 4; ++k) {
    // phase 1: convert + LDS write (waits vmcnt via data dep)
    #pragma unroll
    for (int i = 0; i < 4; ++i) {
      const int ch  = tid + i * 256;
      const int row = ch >> 3;
      const int kg  = ch & 7;
      short8 sa, sw;
      #pragma unroll
      for (int j = 0; j < 4; ++j) {
        sa[j]     = (short)f2bf(pa0[i][j]);
        sa[j + 4] = (short)f2bf(pa1[i][j]);
        sw[j]     = (short)f2bf(pw0[i][j]);
        sw[j + 4] = (short)f2bf(pw1[i][j]);
      }
      const int byte = row * 128 + ((kg * 16) ^ ((row & 7) << 4));
      *reinterpret_cast<short8*>(reinterpret_cast<char*>(As) + byte) = sa;
      *reinterpret_cast<short8*>(reinterpret_cast<char*>(Bs) + byte) = sw;
    }
    if (k < 3) load_tiles((k + 1) * 64);

    asm volatile("s_waitcnt lgkmcnt(0)" ::: "memory");
    __builtin_amdgcn_sched_barrier(0);
    __builtin_amdgcn_s_barrier();
    __builtin_amdgcn_sched_barrier(0);

    // phase 2: fragments + MFMA
    #pragma unroll
    for (int ks = 0; ks < 2; ++ks) {
      const int kb = (ks * 32 + (lane >> 4) * 8) * 2;
      short8 af[4], bf[4];
      #pragma unroll
      for (int mi = 0; mi < 4; ++mi) {
        const int row = wm * 64 + mi * 16 + (lane & 15);
        const int byte = row * 128 + (kb ^ ((row & 7) << 4));
        af[mi] = *reinterpret_cast<const short8*>(
            reinterpret_cast<const char*>(As) + byte);
      }
      #pragma unroll
      for (int ni = 0; ni < 4; ++ni) {
        const int col = wn * 64 + ni * 16 + (lane & 15);
        const int byte = col * 128 + (kb ^ ((col & 7) << 4));
        bf[ni] = *reinterpret_cast<const short8*>(
            reinterpret_cast<const char*>(Bs) + byte);
      }
      #pragma unroll
      for (int mi = 0; mi < 4; ++mi)
        #pragma unroll
        for (int ni = 0; ni < 4; ++ni)
          acc[mi][ni] = __builtin_amdgcn_mfma_f32_16x16x32_bf16(
              af[mi], bf[ni], acc[mi][ni], 0, 0, 0);
    }

    asm volatile("s_waitcnt lgkmcnt(0)" ::: "memory");
    __builtin_amdgcn_sched_barrier(0);
    __builtin_amdgcn_s_barrier();
    __builtin_amdgcn_sched_barrier(0);
  }

  // epilogue: C/D layout col=lane&15, row=(lane>>4)*4+reg
  #pragma unroll
  for (int mi = 0; mi < 4; ++mi) {
    const int row = r0 + wm * 64 + mi * 16 + (lane >> 4) * 4;
    #pragma unroll
    for (int ni = 0; ni < 4; ++ni) {
      const int col = c0 + wn * 64 + ni * 16 + (lane & 15);
      #pragma unroll
      for (int j = 0; j < 4; ++j)
        out[(size_t)(row + j) * DM + col] = (_Float16)(acc[mi][ni][j] + bv[ni]);
    }
  }
}

// ---------------------------------------------------------------------------
// Sampler v4. Block = 512 threads = 8 queries, XCD-swizzled grid
// (n = blockIdx&7 -> batch n's 1.97 MB f16 value slice L2-resident).
// Prep (t<256): thread -> (q=t>>5, m=(t>>2)&7, sub=t&3). Direct 8B global
// loads of its 4 offs + 4 logits (no LDS staging -- each value consumed by
// exactly one thread); 4-lane __shfl_xor softmax; writes per-tap
// {half2(wa,wb), row0*512, row1*512} uint4 into 17-stride LDS.
// Gather (all 512): thread -> (q=wave, m=l>>3, dg=l&3, th=(l>>2)&1);
// th handles 8 of 16 taps (halved latency chain); partner reduce via
// __shfl_xor(acc,4); th==0 lanes store.
// ---------------------------------------------------------------------------
__global__ __launch_bounds__(512) void sample_k(
    const _Float16* __restrict__ proj,    // (N*LQ, 256) f16
    const float* __restrict__ refp,       // (N, LQ, 4)
    const _Float16* __restrict__ value,   // (N, 3840, 256) f16, c = m*32+d
    float* __restrict__ out)              // (N, LQ, 256)
{
  __shared__ uint4 tap_s[8][136];   // [q][m*17 + tap], 17.4 KB

  const int d     = blockIdx.x;
  const int n     = d & 7;
  const int chunk = d >> 3;
  const int row0q = n * LQn + chunk * 8;
  const int t     = threadIdx.x;

  const int lens[4]   = {2048, 1024, 512, 256};
  const int starts[4] = {0, 2048, 3072, 3584};

  // ---- prep: softmax + tap table ----
  if (t < 256) {
    const int q   = t >> 5;
    const int m   = (t >> 2) & 7;
    const int sub = t & 3;              // == level l
    const int j0  = m * 16 + sub * 4;
    const size_t prow = (size_t)(row0q + q) * DM;

    const half4 offv = *reinterpret_cast<const half4*>(&proj[prow + j0]);
    const half4 lgv  = *reinterpret_cast<const half4*>(&proj[prow + 128 + j0]);
    float lg[4], off[4];
    #pragma unroll
    for (int i = 0; i < 4; ++i) { lg[i] = (float)lgv[i]; off[i] = (float)offv[i]; }

    float mx = fmaxf(fmaxf(lg[0], lg[1]), fmaxf(lg[2], lg[3]));
    mx = fmaxf(mx, __shfl_xor(mx, 1));
    mx = fmaxf(mx, __shfl_xor(mx, 2));
    float e[4], s = 0.f;
    #pragma unroll
    for (int i = 0; i < 4; ++i) { e[i] = __expf(lg[i] - mx); s += e[i]; }
    s += __shfl_xor(s, 1);
    s += __shfl_xor(s, 2);
    const float inv = 1.f / s;

    const int   T  = lens[sub];
    const int   st = starts[sub];
    const float fT = (float)T;
    const float rf = refp[(size_t)(row0q + q) * 4 + sub];
    #pragma unroll
    for (int i = 0; i < 4; ++i) {
      const float a  = e[i] * inv;
      const float ix = fmaf(rf, fT, off[i] - 0.5f);
      const float fl = floorf(ix);
      const float w1 = ix - fl;
      const int   i0 = (int)fl;
      const int   i1 = i0 + 1;
      const float wa = (i0 >= 0 && i0 < T) ? a * (1.f - w1) : 0.f;
      const float wb = (i1 >= 0 && i1 < T) ? a * w1 : 0.f;
      const int   r0b = (st + min(max(i0, 0), T - 1)) * 512;
      const int   r1b = (st + min(max(i1, 0), T - 1)) * 512;
      union { half2v h; unsigned u; } pw;
      pw.h.x = (_Float16)wa; pw.h.y = (_Float16)wb;
      uint4 ent; ent.x = pw.u; ent.y = (unsigned)r0b; ent.z = (unsigned)r1b; ent.w = 0u;
      tap_s[q][m * 17 + sub * 4 + i] = ent;
    }
  }
  __syncthreads();

  // ---- gather ----
  const int q  = t >> 6;          // wave id = query
  const int l  = t & 63;
  const int m  = l >> 3;
  const int dg = l & 3;
  const int th = (l >> 2) & 1;    // tap-half
  const char* vb = reinterpret_cast<const char*>(value) +
                   (size_t)n * S_TOT * 512 + m * 64 + dg * 16;

  float acc[8] = {};
  #pragma unroll
  for (int i = 0; i < 8; ++i) {
    const uint4 e = tap_s[q][m * 17 + th * 8 + i];
    union { unsigned u; half2v h; } pw; pw.u = e.x;
    const float wa = (float)pw.h.x;
    const float wb = (float)pw.h.y;
    const half8 v0 = *reinterpret_cast<const half8*>(vb + e.y);
    const half8 v1 = *reinterpret_cast<const half8*>(vb + e.z);
    #pragma unroll
    for (int j = 0; j < 8; ++j)
      acc[j] = fmaf(wa, (float)v0[j], fmaf(wb, (float)v1[j], acc[j]));
  }

  #pragma unroll
  for (int j = 0; j < 8; ++j) acc[j] += __shfl_xor(acc[j], 4);

  if (th == 0) {
    float* op = &out[(size_t)(row0q + q) * DM + m * 32 + dg * 8];
    f32x4 o0 = {acc[0], acc[1], acc[2], acc[3]};
    f32x4 o1 = {acc[4], acc[5], acc[6], acc[7]};
    *reinterpret_cast<f32x4*>(op)     = o0;
    *reinterpret_cast<f32x4*>(op + 4) = o1;
  }
}

}  // namespace

extern "C" void kernel_launch(void* const* d_in, const int* in_sizes, int n_in,
                              void* d_out, int out_size, void* d_ws, size_t ws_size,
                              hipStream_t stream) {
  const float* query  = (const float*)d_in[0];   // (8,2048,256)
  const float* refp   = (const float*)d_in[1];   // (8,2048,4,1)
  const float* inflat = (const float*)d_in[2];   // (8,3840,256)
  const float* W_val  = (const float*)d_in[5];   // (256,256)
  const float* b_val  = (const float*)d_in[6];   // (256,)
  const float* W_off  = (const float*)d_in[7];   // (128,256)
  const float* b_off  = (const float*)d_in[8];   // (128,)
  const float* W_attn = (const float*)d_in[9];   // (128,256)
  const float* b_attn = (const float*)d_in[10];  // (128,)
  float* out = (float*)d_out;

  // workspace: value f16 (30720*256 = 15.73 MB) | proj f16 (16384*256 = 8.4 MB)
  _Float16* value_h = (_Float16*)d_ws;
  _Float16* proj_h  = (_Float16*)((char*)d_ws +
                      (size_t)NB * S_TOT * DM * sizeof(_Float16));

  // merged GEMM: 480 value blocks + 256 proj blocks
  gemm_bf16_k<<<dim3(736), dim3(256), 0, stream>>>(
      inflat, query, W_val, b_val, W_off, b_off, W_attn, b_attn,
      value_h, proj_h);

  // softmax + bilinear sampling + head-mix (XCD-swizzled grid)
  sample_k<<<dim3(NB * LQn / 8), dim3(512), 0, stream>>>(
      proj_h, refp, value_h, out);
}